// Round 2
// baseline (1294.742 us; speedup 1.0000x reference)
//
#include <hip/hip_runtime.h>

typedef float f32x4 __attribute__((ext_vector_type(4)));
typedef __bf16 bf16x8 __attribute__((ext_vector_type(8)));

#define NSTAGE 20
#define TSEQ   2048
#define NST    128
#define NP2    256
#define NCLS   202

static __device__ __forceinline__ unsigned short f2b(float f) {
  return __builtin_bit_cast(unsigned short, (__bf16)f);
}

// ---------------------------------------------------------------------------
// Kernel 1: convert weights to bf16 in ws, with MFMA-friendly layouts.
//  Wt   [64][2048]  = W_embed^T
//  Bws  [20][256][64]: row n'=2n+p holds B_{re/im}[s][n][k] along k
//  Cws  [20][64][256]: row d holds (C_re[s][d][n], -C_im[s][d][n]) interleaved
//  Wclst[208][64]   = W_cls^T, rows >=202 zero
// ---------------------------------------------------------------------------
__global__ void lru_convert_kernel(const float* __restrict__ Wemb,
                                   const float* __restrict__ Bre, const float* __restrict__ Bim,
                                   const float* __restrict__ Cre, const float* __restrict__ Cim,
                                   const float* __restrict__ Wcls,
                                   unsigned short* __restrict__ Wt,
                                   unsigned short* __restrict__ Bws,
                                   unsigned short* __restrict__ Cws,
                                   unsigned short* __restrict__ Wclst)
{
  const int NWT = 64 * 2048;          // 131072
  const int NB  = NSTAGE * NP2 * 64;  // 327680
  const int NC  = NSTAGE * 64 * NP2;  // 327680
  const int NWC = 208 * 64;           // 13312
  int idx = blockIdx.x * 256 + threadIdx.x;
  if (idx < NWT) {
    int d = idx >> 11, k = idx & 2047;
    Wt[idx] = f2b(Wemb[k * 64 + d]);
  } else if (idx < NWT + NB) {
    int r = idx - NWT;
    int s = r / (NP2 * 64); int r2 = r % (NP2 * 64);
    int np = r2 >> 6, k = r2 & 63;
    int n = np >> 1, p = np & 1;
    float v = p ? Bim[(s * NST + n) * 64 + k] : Bre[(s * NST + n) * 64 + k];
    Bws[r] = f2b(v);
  } else if (idx < NWT + NB + NC) {
    int r = idx - NWT - NB;
    int s = r / (64 * NP2); int r2 = r % (64 * NP2);
    int d = r2 >> 8, np = r2 & 255;
    int n = np >> 1, p = np & 1;
    float v = p ? -Cim[(s * 64 + d) * NST + n] : Cre[(s * 64 + d) * NST + n];
    Cws[r] = f2b(v);
  } else if (idx < NWT + NB + NC + NWC) {
    int r = idx - NWT - NB - NC;
    int cls = r >> 6, k = r & 63;
    Wclst[r] = (cls < NCLS) ? f2b(Wcls[k * NCLS + cls]) : (unsigned short)0;
  }
}

// ---------------------------------------------------------------------------
// Kernel 2: LN0 + embed GEMM (16384x2048 @ 2048x64), bf16 MFMA.
// 512 blocks x 256 threads; block = (batch, 32-token chunk).
// ---------------------------------------------------------------------------
__launch_bounds__(256)
__global__ void lru_embed_kernel(const float* __restrict__ x,
                                 const float* __restrict__ g0,
                                 const float* __restrict__ b0,
                                 const unsigned short* __restrict__ Wt,
                                 const float* __restrict__ bemb,
                                 float* __restrict__ h0)
{
  __shared__ __align__(16) unsigned short As[32][72];
  __shared__ float mu_s[32], rs_s[32];

  const int tid = threadIdx.x;
  const int b = blockIdx.x >> 6;
  const int t0 = (blockIdx.x & 63) * 32;
  const int w = tid >> 6, lane = tid & 63;
  const int cl = lane & 15, q = lane >> 4;

  // LN0 statistics: wave w -> tokens w*8 .. w*8+7
  for (int i = 0; i < 8; ++i) {
    int t = w * 8 + i;
    const float* xp = x + ((size_t)(b * TSEQ + t0 + t)) * 2048;
    float sum = 0.f, sq = 0.f;
    for (int j = 0; j < 32; ++j) {
      float v = xp[lane + 64 * j];
      sum += v; sq += v * v;
    }
    for (int m = 1; m < 64; m <<= 1) {
      sum += __shfl_xor(sum, m); sq += __shfl_xor(sq, m);
    }
    if (lane == 0) {
      float mu = sum * (1.f / 2048.f);
      float var = sq * (1.f / 2048.f) - mu * mu;
      mu_s[t] = mu;
      rs_s[t] = rsqrtf(var + 1e-5f);
    }
  }
  __syncthreads();

  const int tt  = w >> 1;              // token-tile 0..1
  const int dt0 = (w & 1) * 2;         // d-tiles {0,1} or {2,3}
  const int st  = tid >> 3;            // staging token 0..31
  const int k8  = (tid & 7) * 8;       // staging k offset
  const float muT = mu_s[st];
  const float rsT = rs_s[st];

  f32x4 acc0 = {0.f, 0.f, 0.f, 0.f}, acc1 = {0.f, 0.f, 0.f, 0.f};
  for (int kc = 0; kc < 32; ++kc) {
    __syncthreads();
    {
      const float* xp = x + ((size_t)(b * TSEQ + t0 + st)) * 2048 + kc * 64 + k8;
      float4 xa = *(const float4*)xp;
      float4 xb = *(const float4*)(xp + 4);
      float4 ga = *(const float4*)&g0[kc * 64 + k8];
      float4 gb = *(const float4*)&g0[kc * 64 + k8 + 4];
      float4 ba = *(const float4*)&b0[kc * 64 + k8];
      float4 bbv = *(const float4*)&b0[kc * 64 + k8 + 4];
      float a0v = (xa.x - muT) * rsT * ga.x + ba.x;
      float a1v = (xa.y - muT) * rsT * ga.y + ba.y;
      float a2v = (xa.z - muT) * rsT * ga.z + ba.z;
      float a3v = (xa.w - muT) * rsT * ga.w + ba.w;
      float a4v = (xb.x - muT) * rsT * gb.x + bbv.x;
      float a5v = (xb.y - muT) * rsT * gb.y + bbv.y;
      float a6v = (xb.z - muT) * rsT * gb.z + bbv.z;
      float a7v = (xb.w - muT) * rsT * gb.w + bbv.w;
      uint4 u;
      u.x = (unsigned)f2b(a0v) | ((unsigned)f2b(a1v) << 16);
      u.y = (unsigned)f2b(a2v) | ((unsigned)f2b(a3v) << 16);
      u.z = (unsigned)f2b(a4v) | ((unsigned)f2b(a5v) << 16);
      u.w = (unsigned)f2b(a6v) | ((unsigned)f2b(a7v) << 16);
      *(uint4*)((char*)&As[0][0] + st * 144 + k8 * 2) = u;
    }
    __syncthreads();
    for (int ks = 0; ks < 2; ++ks) {
      bf16x8 a = *(const bf16x8*)((const char*)&As[0][0] + (tt * 16 + cl) * 144 + ks * 64 + q * 16);
      const unsigned short* wp = Wt + ((size_t)(dt0 * 16 + cl)) * 2048 + kc * 64 + ks * 32 + q * 8;
      bf16x8 w0 = *(const bf16x8*)wp;
      bf16x8 w1 = *(const bf16x8*)(wp + 16 * 2048);
      acc0 = __builtin_amdgcn_mfma_f32_16x16x32_bf16(a, w0, acc0, 0, 0, 0);
      acc1 = __builtin_amdgcn_mfma_f32_16x16x32_bf16(a, w1, acc1, 0, 0, 0);
    }
  }
  {
    int da = dt0 * 16 + cl, db = (dt0 + 1) * 16 + cl;
    float bea = bemb[da], beb = bemb[db];
    for (int r = 0; r < 4; ++r) {
      int t = tt * 16 + q * 4 + r;
      size_t row = ((size_t)(b * TSEQ + t0 + t)) * 64;
      h0[row + da] = acc0[r] + bea;
      h0[row + db] = acc1[r] + beb;
    }
  }
}

// ---------------------------------------------------------------------------
// Kernel 3a (per stage): LN -> B-proj MFMA -> 16-step local scan -> carry.
// Block = (batch b, 16-token chunk c); 1024 blocks.
// ---------------------------------------------------------------------------
__launch_bounds__(256)
__global__ void lru_carry_kernel(const float* __restrict__ h0,
                                 float* __restrict__ carr,
                                 const unsigned short* __restrict__ Bws,
                                 const float* __restrict__ lng,
                                 const float* __restrict__ lnb,
                                 const float* __restrict__ nulog,
                                 const float* __restrict__ thlog,
                                 const float* __restrict__ gmlog,
                                 int s)
{
  __shared__ __align__(16) unsigned short zb[16][72];
  __shared__ __align__(16) float ucat[16][264];

  const int tid = threadIdx.x;
  const int b = blockIdx.x >> 7;
  const int c = blockIdx.x & 127;
  const int t0 = c * 16;

  const int tg = tid >> 4;
  const int g  = tid & 15;
  const int w  = tid >> 6;
  const int lane = tid & 63;
  const int cl = lane & 15;
  const int q  = lane >> 4;

  // LayerNorm over D=64 directly from h0 (16-lane subgroup per token)
  {
    float4 hv = *(const float4*)&h0[((size_t)(b * TSEQ + t0 + tg)) * 64 + g * 4];
    float sum = hv.x + hv.y + hv.z + hv.w;
    sum += __shfl_xor(sum, 1); sum += __shfl_xor(sum, 2);
    sum += __shfl_xor(sum, 4); sum += __shfl_xor(sum, 8);
    float mu = sum * (1.f / 64.f);
    float d0 = hv.x - mu, d1 = hv.y - mu, d2 = hv.z - mu, d3 = hv.w - mu;
    float sq = d0 * d0 + d1 * d1 + d2 * d2 + d3 * d3;
    sq += __shfl_xor(sq, 1); sq += __shfl_xor(sq, 2);
    sq += __shfl_xor(sq, 4); sq += __shfl_xor(sq, 8);
    float rs = rsqrtf(sq * (1.f / 64.f) + 1e-5f);
    float4 gv = *(const float4*)&lng[s * 64 + g * 4];
    float4 bv = *(const float4*)&lnb[s * 64 + g * 4];
    float z0 = d0 * rs * gv.x + bv.x;
    float z1 = d1 * rs * gv.y + bv.y;
    float z2 = d2 * rs * gv.z + bv.z;
    float z3 = d3 * rs * gv.w + bv.w;
    *(unsigned*)&zb[tg][g * 4]     = (unsigned)f2b(z0) | ((unsigned)f2b(z1) << 16);
    *(unsigned*)&zb[tg][g * 4 + 2] = (unsigned)f2b(z2) | ((unsigned)f2b(z3) << 16);
  }
  __syncthreads();

  // U = Z * B^T scaled by gamma (MFMA)
  {
    bf16x8 a0 = *(const bf16x8*)((const char*)&zb[0][0] + cl * 144 + q * 16);
    bf16x8 a1 = *(const bf16x8*)((const char*)&zb[0][0] + cl * 144 + 64 + q * 16);
    const unsigned short* bb = Bws + (size_t)s * NP2 * 64;
    for (int ti = 0; ti < 4; ++ti) {
      int np0 = (w * 4 + ti) * 16;
      const unsigned short* bp = bb + (np0 + cl) * 64 + q * 8;
      bf16x8 b0 = *(const bf16x8*)bp;
      bf16x8 b1 = *(const bf16x8*)(bp + 32);
      f32x4 acc = {0.f, 0.f, 0.f, 0.f};
      acc = __builtin_amdgcn_mfma_f32_16x16x32_bf16(a0, b0, acc, 0, 0, 0);
      acc = __builtin_amdgcn_mfma_f32_16x16x32_bf16(a1, b1, acc, 0, 0, 0);
      int np = np0 + cl;
      float gam = __expf(gmlog[s * NST + (np >> 1)]);
      ucat[q * 4 + 0][np] = acc[0] * gam;
      ucat[q * 4 + 1][np] = acc[1] * gam;
      ucat[q * 4 + 2][np] = acc[2] * gam;
      ucat[q * 4 + 3][np] = acc[3] * gam;
    }
  }
  __syncthreads();

  // local 16-step complex scan per state n -> carry
  if (tid < NST) {
    int n = tid;
    float mag = __expf(-__expf(nulog[s * NST + n]));
    float th  = __expf(thlog[s * NST + n]);
    float lamr = mag * __cosf(th);
    float lami = mag * __sinf(th);
    float hr = 0.f, hi = 0.f;
    #pragma unroll
    for (int t = 0; t < 16; ++t) {
      float ur = ucat[t][2 * n], ui = ucat[t][2 * n + 1];
      float nr = fmaf(lamr, hr, fmaf(-lami, hi, ur));
      float ni = fmaf(lamr, hi, fmaf(lami, hr, ui));
      hr = nr; hi = ni;
    }
    float* cp = carr + ((size_t)(b * 128 + c)) * 256 + n * 2;
    cp[0] = hr;
    cp[1] = hi;
  }
}

// ---------------------------------------------------------------------------
// Kernel 3b (per stage): LN -> B-proj -> local scan -> prefix from carries ->
// C-proj -> h update. If last stage, fuse classifier and write out.
// ---------------------------------------------------------------------------
__launch_bounds__(256)
__global__ void lru_apply_kernel(float* __restrict__ h0,
                                 const float* __restrict__ carr,
                                 const unsigned short* __restrict__ Bws,
                                 const unsigned short* __restrict__ Cws,
                                 const float* __restrict__ lng,
                                 const float* __restrict__ lnb,
                                 const float* __restrict__ nulog,
                                 const float* __restrict__ thlog,
                                 const float* __restrict__ gmlog,
                                 const float* __restrict__ dskip,
                                 int s, int last,
                                 const unsigned short* __restrict__ Wclst,
                                 const float* __restrict__ bcls,
                                 float* __restrict__ out)
{
  __shared__ __align__(16) float hsm[16][68];
  __shared__ __align__(16) float zsm[16][68];
  __shared__ __align__(16) unsigned short zb[16][72];
  __shared__ __align__(16) float ucat[16][264];
  __shared__ __align__(16) unsigned short hcb[16][264];

  const int tid = threadIdx.x;
  const int b = blockIdx.x >> 7;
  const int c = blockIdx.x & 127;
  const int t0 = c * 16;

  const int tg = tid >> 4;
  const int g  = tid & 15;
  const int w  = tid >> 6;
  const int lane = tid & 63;
  const int cl = lane & 15;
  const int q  = lane >> 4;

  // load h tile + LayerNorm
  {
    float4 hv = *(const float4*)&h0[((size_t)(b * TSEQ + t0 + tg)) * 64 + g * 4];
    hsm[tg][g * 4 + 0] = hv.x; hsm[tg][g * 4 + 1] = hv.y;
    hsm[tg][g * 4 + 2] = hv.z; hsm[tg][g * 4 + 3] = hv.w;
    float sum = hv.x + hv.y + hv.z + hv.w;
    sum += __shfl_xor(sum, 1); sum += __shfl_xor(sum, 2);
    sum += __shfl_xor(sum, 4); sum += __shfl_xor(sum, 8);
    float mu = sum * (1.f / 64.f);
    float d0 = hv.x - mu, d1 = hv.y - mu, d2 = hv.z - mu, d3 = hv.w - mu;
    float sq = d0 * d0 + d1 * d1 + d2 * d2 + d3 * d3;
    sq += __shfl_xor(sq, 1); sq += __shfl_xor(sq, 2);
    sq += __shfl_xor(sq, 4); sq += __shfl_xor(sq, 8);
    float rs = rsqrtf(sq * (1.f / 64.f) + 1e-5f);
    float4 gv = *(const float4*)&lng[s * 64 + g * 4];
    float4 bv = *(const float4*)&lnb[s * 64 + g * 4];
    float z0 = d0 * rs * gv.x + bv.x;
    float z1 = d1 * rs * gv.y + bv.y;
    float z2 = d2 * rs * gv.z + bv.z;
    float z3 = d3 * rs * gv.w + bv.w;
    zsm[tg][g * 4 + 0] = z0; zsm[tg][g * 4 + 1] = z1;
    zsm[tg][g * 4 + 2] = z2; zsm[tg][g * 4 + 3] = z3;
    *(unsigned*)&zb[tg][g * 4]     = (unsigned)f2b(z0) | ((unsigned)f2b(z1) << 16);
    *(unsigned*)&zb[tg][g * 4 + 2] = (unsigned)f2b(z2) | ((unsigned)f2b(z3) << 16);
  }
  __syncthreads();

  // U = Z * B^T scaled by gamma (MFMA)
  {
    bf16x8 a0 = *(const bf16x8*)((const char*)&zb[0][0] + cl * 144 + q * 16);
    bf16x8 a1 = *(const bf16x8*)((const char*)&zb[0][0] + cl * 144 + 64 + q * 16);
    const unsigned short* bb = Bws + (size_t)s * NP2 * 64;
    for (int ti = 0; ti < 4; ++ti) {
      int np0 = (w * 4 + ti) * 16;
      const unsigned short* bp = bb + (np0 + cl) * 64 + q * 8;
      bf16x8 b0 = *(const bf16x8*)bp;
      bf16x8 b1 = *(const bf16x8*)(bp + 32);
      f32x4 acc = {0.f, 0.f, 0.f, 0.f};
      acc = __builtin_amdgcn_mfma_f32_16x16x32_bf16(a0, b0, acc, 0, 0, 0);
      acc = __builtin_amdgcn_mfma_f32_16x16x32_bf16(a1, b1, acc, 0, 0, 0);
      int np = np0 + cl;
      float gam = __expf(gmlog[s * NST + (np >> 1)]);
      ucat[q * 4 + 0][np] = acc[0] * gam;
      ucat[q * 4 + 1][np] = acc[1] * gam;
      ucat[q * 4 + 2][np] = acc[2] * gam;
      ucat[q * 4 + 3][np] = acc[3] * gam;
    }
  }
  __syncthreads();

  // local scan + prefix from carries + apply -> hcb (bf16)
  if (tid < NST) {
    int n = tid;
    float mag = __expf(-__expf(nulog[s * NST + n]));
    float th  = __expf(thlog[s * NST + n]);
    float lamr = mag * __cosf(th);
    float lami = mag * __sinf(th);
    float hr = 0.f, hi = 0.f;
    #pragma unroll
    for (int t = 0; t < 16; ++t) {
      float ur = ucat[t][2 * n], ui = ucat[t][2 * n + 1];
      float nr = fmaf(lamr, hr, fmaf(-lami, hi, ur));
      float ni = fmaf(lamr, hi, fmaf(lami, hr, ui));
      hr = nr; hi = ni;
      ucat[t][2 * n] = hr; ucat[t][2 * n + 1] = hi;
    }
    // lam^16
    float ar = lamr, ai = lami;
    #pragma unroll
    for (int it = 0; it < 4; ++it) {
      float nr = ar * ar - ai * ai;
      float ni = 2.f * ar * ai;
      ar = nr; ai = ni;
    }
    // prefix over earlier chunks of this batch
    float Pr = 0.f, Pi = 0.f;
    const float* cb = carr + ((size_t)b * 128) * 256 + n * 2;
    for (int j = 0; j < c; ++j) {
      float cr = cb[j * 256];
      float ci = cb[j * 256 + 1];
      float nr = fmaf(ar, Pr, fmaf(-ai, Pi, cr));
      float ni = fmaf(ar, Pi, fmaf(ai, Pr, ci));
      Pr = nr; Pi = ni;
    }
    // apply: h_t(global) = h_t(local) + lam^{t+1} * P
    float mr = lamr, mi = lami;
    #pragma unroll
    for (int t = 0; t < 16; ++t) {
      float hgr = ucat[t][2 * n]     + mr * Pr - mi * Pi;
      float hgi = ucat[t][2 * n + 1] + mr * Pi + mi * Pr;
      *(unsigned*)&hcb[t][2 * n] = (unsigned)f2b(hgr) | ((unsigned)f2b(hgi) << 16);
      float nmr = mr * lamr - mi * lami;
      float nmi = mr * lami + mi * lamr;
      mr = nmr; mi = nmi;
    }
  }
  __syncthreads();

  // Y = Hcat * Cc (MFMA, K=256); h += y + Dskip*z
  {
    int d0 = w * 16;
    const unsigned short* cp = Cws + ((size_t)s * 64 + d0 + cl) * NP2 + q * 8;
    f32x4 acc = {0.f, 0.f, 0.f, 0.f};
    #pragma unroll
    for (int ks = 0; ks < 8; ++ks) {
      bf16x8 a  = *(const bf16x8*)((const char*)&hcb[0][0] + cl * 528 + ks * 64 + q * 16);
      bf16x8 cc = *(const bf16x8*)(cp + ks * 32);
      acc = __builtin_amdgcn_mfma_f32_16x16x32_bf16(a, cc, acc, 0, 0, 0);
    }
    int d = d0 + cl;
    float dk = dskip[s * 64 + d];
    #pragma unroll
    for (int r = 0; r < 4; ++r) {
      int t = q * 4 + r;
      hsm[t][d] = hsm[t][d] + acc[r] + dk * zsm[t][d];
    }
  }
  __syncthreads();

  if (!last) {
    // store updated h tile
    float4 hv;
    hv.x = hsm[tg][g * 4 + 0]; hv.y = hsm[tg][g * 4 + 1];
    hv.z = hsm[tg][g * 4 + 2]; hv.w = hsm[tg][g * 4 + 3];
    *(float4*)&h0[((size_t)(b * TSEQ + t0 + tg)) * 64 + g * 4] = hv;
  } else {
    // classifier: out = h @ W_cls + b_cls
    {
      float4 hv;
      hv.x = hsm[tg][g * 4 + 0]; hv.y = hsm[tg][g * 4 + 1];
      hv.z = hsm[tg][g * 4 + 2]; hv.w = hsm[tg][g * 4 + 3];
      *(unsigned*)&zb[tg][g * 4]     = (unsigned)f2b(hv.x) | ((unsigned)f2b(hv.y) << 16);
      *(unsigned*)&zb[tg][g * 4 + 2] = (unsigned)f2b(hv.z) | ((unsigned)f2b(hv.w) << 16);
    }
    __syncthreads();
    bf16x8 a0 = *(const bf16x8*)((const char*)&zb[0][0] + cl * 144 + q * 16);
    bf16x8 a1 = *(const bf16x8*)((const char*)&zb[0][0] + cl * 144 + 64 + q * 16);
    for (int ti = w; ti < 13; ti += 4) {
      int cls0 = ti * 16;
      const unsigned short* wp = Wclst + (cls0 + cl) * 64 + q * 8;
      bf16x8 b0 = *(const bf16x8*)wp;
      bf16x8 b1 = *(const bf16x8*)(wp + 32);
      f32x4 acc = {0.f, 0.f, 0.f, 0.f};
      acc = __builtin_amdgcn_mfma_f32_16x16x32_bf16(a0, b0, acc, 0, 0, 0);
      acc = __builtin_amdgcn_mfma_f32_16x16x32_bf16(a1, b1, acc, 0, 0, 0);
      int cls = cls0 + cl;
      if (cls < NCLS) {
        float bc = bcls[cls];
        #pragma unroll
        for (int r = 0; r < 4; ++r) {
          int t = q * 4 + r;
          out[((size_t)(b * TSEQ + t0 + t)) * NCLS + cls] = acc[r] + bc;
        }
      }
    }
  }
}

// ---------------------------------------------------------------------------
extern "C" void kernel_launch(void* const* d_in, const int* in_sizes, int n_in,
                              void* d_out, int out_size, void* d_ws, size_t ws_size,
                              hipStream_t stream) {
  (void)in_sizes; (void)n_in; (void)out_size; (void)ws_size;
  const float* x     = (const float*)d_in[0];
  const float* ln0g  = (const float*)d_in[1];
  const float* ln0b  = (const float*)d_in[2];
  const float* Wemb  = (const float*)d_in[3];
  const float* bemb  = (const float*)d_in[4];
  const float* lng   = (const float*)d_in[5];
  const float* lnb   = (const float*)d_in[6];
  const float* nulog = (const float*)d_in[7];
  const float* thlog = (const float*)d_in[8];
  const float* gmlog = (const float*)d_in[9];
  const float* Bre   = (const float*)d_in[10];
  const float* Bim   = (const float*)d_in[11];
  const float* Cre   = (const float*)d_in[12];
  const float* Cim   = (const float*)d_in[13];
  const float* dskip = (const float*)d_in[14];
  const float* Wcls  = (const float*)d_in[15];
  const float* bcls  = (const float*)d_in[16];
  float* out = (float*)d_out;

  char* ws = (char*)d_ws;
  // ws layout (bytes):
  //  h0    @0        : 16384*64*4      = 4194304
  //  carr  @4194304  : 8*128*256*4     = 1048576
  //  Bws   @5242880  : 20*256*64*2     = 655360
  //  Cws   @5898240  : 20*64*256*2     = 655360
  //  Wt    @6553600  : 64*2048*2       = 262144
  //  Wclst @6815744  : 208*64*2        = 26624   (end 6842368)
  float* h0            = (float*)(ws + 0);
  float* carr          = (float*)(ws + 4194304);
  unsigned short* Bws  = (unsigned short*)(ws + 5242880);
  unsigned short* Cws  = (unsigned short*)(ws + 5898240);
  unsigned short* Wt   = (unsigned short*)(ws + 6553600);
  unsigned short* Wcl  = (unsigned short*)(ws + 6815744);

  lru_convert_kernel<<<3124, 256, 0, stream>>>(Wemb, Bre, Bim, Cre, Cim, Wcls,
                                               Wt, Bws, Cws, Wcl);
  lru_embed_kernel<<<512, 256, 0, stream>>>(x, ln0g, ln0b, Wt, bemb, h0);

  for (int s = 0; s < NSTAGE; ++s) {
    lru_carry_kernel<<<1024, 256, 0, stream>>>(h0, carr, Bws, lng, lnb,
                                               nulog, thlog, gmlog, s);
    lru_apply_kernel<<<1024, 256, 0, stream>>>(h0, carr, Bws, Cws, lng, lnb,
                                               nulog, thlog, gmlog, dskip,
                                               s, (s == NSTAGE - 1) ? 1 : 0,
                                               Wcl, bcls, out);
  }
}